// Round 1
// baseline (1540.306 us; speedup 1.0000x reference)
//
#include <hip/hip_runtime.h>

#define NHEAD 16
#define SEQ 2048
#define DMODEL 1024
#define BB 4
#define MROWS (BB*SEQ)      // 8192
#define NBH (BB*NHEAD)      // 64

typedef float f32x4 __attribute__((ext_vector_type(4)));
typedef _Float16 f16x8 __attribute__((ext_vector_type(8)));

static __device__ __forceinline__ f32x4 mfma16(f16x8 a, f16x8 b, f32x4 c) {
  return __builtin_amdgcn_mfma_f32_16x16x32_f16(a, b, c, 0, 0, 0);
}

// fp32 -> f16 hi/lo split: x ~= hi + lo, residual ~2^-22 rel
static __device__ __forceinline__ void split2(float x, unsigned short& hi, unsigned short& lo) {
  _Float16 h = (_Float16)x;
  hi = __builtin_bit_cast(unsigned short, h);
  lo = __builtin_bit_cast(unsigned short, (_Float16)(x - (float)h));
}

// C = X[M,K] @ W[N,K]^T + bias, M=8192 N=1024 K=1024, fp32 in, hi/lo f16 3-MFMA.
// MODE 0: write hi/lo f16 in [B,H,S,64] (Q,K)
// MODE 1: write single f16 transposed [B,H,64,S] (V^T)
// MODE 2: write fp32 [M,N] (final output)
template<int MODE>
__global__ __launch_bounds__(256, 2)
void proj_gemm(const float* __restrict__ X, const float* __restrict__ W,
               const float* __restrict__ bias,
               unsigned short* __restrict__ o_hi, unsigned short* __restrict__ o_lo,
               float* __restrict__ o_f32)
{
  // rows padded 32 -> 40 u16 (80 B) so 16-row ds_read_b128 columns land ~2-way on banks
  __shared__ unsigned short Ah[128][40];
  __shared__ unsigned short Al[128][40];
  __shared__ unsigned short Bh[128][40];
  __shared__ unsigned short Bl[128][40];
  const int tid  = threadIdx.x;
  const int wid  = tid >> 6, lane = tid & 63;
  const int g    = lane >> 4, r16 = lane & 15;
  const int m0   = blockIdx.x * 128, n0 = blockIdx.y * 128;
  const int wr   = wid >> 1, wc = wid & 1;
  const int trow = tid >> 3, tc4 = (tid & 7) << 2;

  f32x4 acc[4][4] = {};

  for (int kt = 0; kt < DMODEL/32; ++kt) {
    __syncthreads();
#pragma unroll
    for (int p = 0; p < 4; ++p) {
      const int row = trow + p*32;
      const float4 xa = *(const float4*)(X + (size_t)(m0+row)*DMODEL + kt*32 + tc4);
      const float4 xb = *(const float4*)(W + (size_t)(n0+row)*DMODEL + kt*32 + tc4);
      ushort4 ah, al, bh4, bl4;
      split2(xa.x, ah.x, al.x); split2(xa.y, ah.y, al.y);
      split2(xa.z, ah.z, al.z); split2(xa.w, ah.w, al.w);
      split2(xb.x, bh4.x, bl4.x); split2(xb.y, bh4.y, bl4.y);
      split2(xb.z, bh4.z, bl4.z); split2(xb.w, bh4.w, bl4.w);
      *(ushort4*)(&Ah[row][tc4]) = ah;
      *(ushort4*)(&Al[row][tc4]) = al;
      *(ushort4*)(&Bh[row][tc4]) = bh4;
      *(ushort4*)(&Bl[row][tc4]) = bl4;
    }
    __syncthreads();
    f16x8 a_h[4], a_l[4], b_h[4], b_l[4];
#pragma unroll
    for (int t = 0; t < 4; ++t) {
      a_h[t] = *(const f16x8*)(&Ah[wr*64 + t*16 + r16][g*8]);
      a_l[t] = *(const f16x8*)(&Al[wr*64 + t*16 + r16][g*8]);
      b_h[t] = *(const f16x8*)(&Bh[wc*64 + t*16 + r16][g*8]);
      b_l[t] = *(const f16x8*)(&Bl[wc*64 + t*16 + r16][g*8]);
    }
#pragma unroll
    for (int mt = 0; mt < 4; ++mt)
#pragma unroll
      for (int nt = 0; nt < 4; ++nt) {
        acc[mt][nt] = mfma16(a_h[mt], b_h[nt], acc[mt][nt]);
        acc[mt][nt] = mfma16(a_h[mt], b_l[nt], acc[mt][nt]);
        acc[mt][nt] = mfma16(a_l[mt], b_h[nt], acc[mt][nt]);
      }
  }

#pragma unroll
  for (int nt = 0; nt < 4; ++nt) {
    const int n  = n0 + wc*64 + nt*16 + r16;
    const float bn = bias[n];
#pragma unroll
    for (int mt = 0; mt < 4; ++mt) {
      const int mb = m0 + wr*64 + mt*16 + g*4;   // C row = 4*(lane>>4)+j
      if (MODE == 0) {
#pragma unroll
        for (int j = 0; j < 4; ++j) {
          const int m = mb + j;
          const float c = acc[mt][nt][j] + bn;
          const int bt = m >> 11, s = m & (SEQ-1);
          const int hh = n >> 6,  d = n & 63;
          const size_t o = (((size_t)(bt*NHEAD + hh)*SEQ + s) << 6) + d;
          unsigned short hi, lo; split2(c, hi, lo);
          o_hi[o] = hi; o_lo[o] = lo;
        }
      } else if (MODE == 1) {
        const int bt = mb >> 11, sb = mb & (SEQ-1);
        const int hh = n >> 6,  d = n & 63;
        ushort4 v;
        v.x = __builtin_bit_cast(unsigned short, (_Float16)(acc[mt][nt][0] + bn));
        v.y = __builtin_bit_cast(unsigned short, (_Float16)(acc[mt][nt][1] + bn));
        v.z = __builtin_bit_cast(unsigned short, (_Float16)(acc[mt][nt][2] + bn));
        v.w = __builtin_bit_cast(unsigned short, (_Float16)(acc[mt][nt][3] + bn));
        *(ushort4*)(o_hi + ((size_t)(bt*NHEAD + hh)*64 + d)*SEQ + sb) = v;
      } else {
#pragma unroll
        for (int j = 0; j < 4; ++j) {
          const int m = mb + j;
          o_f32[(size_t)m*DMODEL + n] = acc[mt][nt][j] + bn;
        }
      }
    }
  }
}

// pass A: per-row online max m and sum l of exp(s-m). Scores via hi/lo QK^T.
__global__ __launch_bounds__(256)
void attn_ml(const unsigned short* __restrict__ Qh, const unsigned short* __restrict__ Ql,
             const unsigned short* __restrict__ Kh, const unsigned short* __restrict__ Kl,
             float* __restrict__ mrow, float* __restrict__ lrow)
{
  const int tid = threadIdx.x, wid = tid >> 6, lane = tid & 63;
  const int g = lane >> 4, r16 = lane & 15;
  const int bh = blockIdx.y;
  const int s0 = blockIdx.x*64 + wid*16;

  const size_t qoff = ((size_t)bh*SEQ + s0 + r16)*64 + (size_t)g*8;
  const f16x8 qh0 = *(const f16x8*)(Qh + qoff);
  const f16x8 qh1 = *(const f16x8*)(Qh + qoff + 32);
  const f16x8 ql0 = *(const f16x8*)(Ql + qoff);
  const f16x8 ql1 = *(const f16x8*)(Ql + qoff + 32);

  float mr[4] = {-1e30f, -1e30f, -1e30f, -1e30f};
  float lp[4] = {0.f, 0.f, 0.f, 0.f};
  const size_t kb = ((size_t)bh*SEQ + r16)*64 + (size_t)g*8;

  for (int kt = 0; kt < SEQ/16; ++kt) {
    const size_t ko = kb + (size_t)kt*16*64;
    const f16x8 kh0 = *(const f16x8*)(Kh + ko);
    const f16x8 kh1 = *(const f16x8*)(Kh + ko + 32);
    const f16x8 kl0 = *(const f16x8*)(Kl + ko);
    const f16x8 kl1 = *(const f16x8*)(Kl + ko + 32);
    f32x4 acc = {};
    acc = mfma16(qh0, kh0, acc); acc = mfma16(qh1, kh1, acc);
    acc = mfma16(qh0, kl0, acc); acc = mfma16(qh1, kl1, acc);
    acc = mfma16(ql0, kh0, acc); acc = mfma16(ql1, kh1, acc);
#pragma unroll
    for (int j = 0; j < 4; ++j) {
      const float sc = acc[j] * 0.125f;
      float tm = sc;
      tm = fmaxf(tm, __shfl_xor(tm, 1));
      tm = fmaxf(tm, __shfl_xor(tm, 2));
      tm = fmaxf(tm, __shfl_xor(tm, 4));
      tm = fmaxf(tm, __shfl_xor(tm, 8));
      const float mn = fmaxf(mr[j], tm);
      lp[j] = lp[j] * __expf(mr[j] - mn) + __expf(sc - mn);
      mr[j] = mn;
    }
  }
#pragma unroll
  for (int j = 0; j < 4; ++j) {
    lp[j] += __shfl_xor(lp[j], 1);
    lp[j] += __shfl_xor(lp[j], 2);
    lp[j] += __shfl_xor(lp[j], 4);
    lp[j] += __shfl_xor(lp[j], 8);
  }
  if (r16 == 0) {
#pragma unroll
    for (int j = 0; j < 4; ++j) {
      const size_t r = (size_t)bh*SEQ + s0 + g*4 + j;
      mrow[r] = mr[j];
      lrow[r] = lp[j];
    }
  }
}

// pass B: recompute scores, write normalized weights (fp32), accumulate O = W @ V.
__global__ __launch_bounds__(256)
void attn_pv(const unsigned short* __restrict__ Qh, const unsigned short* __restrict__ Ql,
             const unsigned short* __restrict__ Kh, const unsigned short* __restrict__ Kl,
             const unsigned short* __restrict__ Vt,
             const float* __restrict__ mrow, const float* __restrict__ lrow,
             float* __restrict__ wout, float* __restrict__ of32)
{
  __shared__ unsigned short PA[4][16][40];   // per-wave P-tile transpose staging
  const int tid = threadIdx.x, wid = tid >> 6, lane = tid & 63;
  const int g = lane >> 4, r16 = lane & 15;
  const int bh = blockIdx.y, bt = bh >> 4, hh = bh & (NHEAD-1);
  const int s0 = blockIdx.x*64 + wid*16;

  const size_t qoff = ((size_t)bh*SEQ + s0 + r16)*64 + (size_t)g*8;
  const f16x8 qh0 = *(const f16x8*)(Qh + qoff);
  const f16x8 qh1 = *(const f16x8*)(Qh + qoff + 32);
  const f16x8 ql0 = *(const f16x8*)(Ql + qoff);
  const f16x8 ql1 = *(const f16x8*)(Ql + qoff + 32);

  float mj[4], li[4];
#pragma unroll
  for (int j = 0; j < 4; ++j) {
    const size_t r = (size_t)bh*SEQ + s0 + g*4 + j;
    mj[j] = mrow[r];
    li[j] = 1.0f / lrow[r];
  }

  f32x4 acco[4] = {};
  const unsigned short* vtb = Vt + (size_t)bh*64*SEQ;
  float* wb = wout + ((size_t)bh*SEQ + s0)*SEQ;
  const size_t kb = ((size_t)bh*SEQ + r16)*64 + (size_t)g*8;

  for (int kt = 0; kt < SEQ/32; ++kt) {
#pragma unroll
    for (int half = 0; half < 2; ++half) {
      const int k0 = kt*32 + half*16;
      const size_t ko = kb + (size_t)k0*64;
      const f16x8 kh0 = *(const f16x8*)(Kh + ko);
      const f16x8 kh1 = *(const f16x8*)(Kh + ko + 32);
      const f16x8 kl0 = *(const f16x8*)(Kl + ko);
      const f16x8 kl1 = *(const f16x8*)(Kl + ko + 32);
      f32x4 acc = {};
      acc = mfma16(qh0, kh0, acc); acc = mfma16(qh1, kh1, acc);
      acc = mfma16(qh0, kl0, acc); acc = mfma16(qh1, kl1, acc);
      acc = mfma16(ql0, kh0, acc); acc = mfma16(ql1, kh1, acc);
#pragma unroll
      for (int j = 0; j < 4; ++j) {
        const float sc = acc[j] * 0.125f;
        const float w  = __expf(sc - mj[j]) * li[j];
        wb[(size_t)(g*4 + j)*SEQ + k0 + r16] = w;
        PA[wid][g*4 + j][half*16 + r16] = __builtin_bit_cast(unsigned short, (_Float16)w);
      }
    }
    asm volatile("s_waitcnt lgkmcnt(0)" ::: "memory");
    const f16x8 pa = *(const f16x8*)(&PA[wid][r16][g*8]);
#pragma unroll
    for (int nt = 0; nt < 4; ++nt) {
      const f16x8 vv = *(const f16x8*)(vtb + (size_t)(nt*16 + r16)*SEQ + kt*32 + g*8);
      acco[nt] = mfma16(pa, vv, acco[nt]);
    }
  }

#pragma unroll
  for (int nt = 0; nt < 4; ++nt)
#pragma unroll
    for (int j = 0; j < 4; ++j)
      of32[((size_t)bt*SEQ + s0 + g*4 + j)*DMODEL + hh*64 + nt*16 + r16] = acco[nt][j];
}

extern "C" void kernel_launch(void* const* d_in, const int* in_sizes, int n_in,
                              void* d_out, int out_size, void* d_ws, size_t ws_size,
                              hipStream_t stream)
{
  const float* query = (const float*)d_in[0];
  const float* key_  = (const float*)d_in[1];
  const float* value = (const float*)d_in[2];
  const float* Wq = (const float*)d_in[3];
  const float* bq = (const float*)d_in[4];
  const float* Wk = (const float*)d_in[5];
  const float* bk = (const float*)d_in[6];
  const float* Wv = (const float*)d_in[7];
  const float* bv = (const float*)d_in[8];
  const float* Wo = (const float*)d_in[9];
  const float* bo = (const float*)d_in[10];

  // workspace layout (~118 MB total)
  char* ws = (char*)d_ws;
  const size_t NE = (size_t)NBH * SEQ * 64;    // 8,388,608 elements per array
  unsigned short* Qh = (unsigned short*)ws;
  unsigned short* Ql = Qh + NE;
  unsigned short* Kh = Ql + NE;
  unsigned short* Kl = Kh + NE;
  unsigned short* Vt = Kl + NE;                // single-f16 V^T [B,H,64,S]
  float* mrow = (float*)(Vt + NE);
  float* lrow = mrow + (size_t)NBH * SEQ;
  float* Of   = lrow + (size_t)NBH * SEQ;      // attn output pre-projection [M, D]

  float* out0  = (float*)d_out;
  float* wattn = out0 + (size_t)MROWS * DMODEL;  // attention weights [B,H,S,S]

  dim3 gg(MROWS/128, DMODEL/128);
  proj_gemm<0><<<gg, dim3(256), 0, stream>>>(query, Wq, bq, Qh, Ql, nullptr);
  proj_gemm<0><<<gg, dim3(256), 0, stream>>>(key_,  Wk, bk, Kh, Kl, nullptr);
  proj_gemm<1><<<gg, dim3(256), 0, stream>>>(value, Wv, bv, Vt, nullptr, nullptr);
  attn_ml<<<dim3(SEQ/64, NBH), dim3(256), 0, stream>>>(Qh, Ql, Kh, Kl, mrow, lrow);
  attn_pv<<<dim3(SEQ/64, NBH), dim3(256), 0, stream>>>(Qh, Ql, Kh, Kl, Vt, mrow, lrow, wattn, Of);
  proj_gemm<2><<<gg, dim3(256), 0, stream>>>(Of, Wo, bo, nullptr, nullptr, out0);
}

// Round 2
// 976.217 us; speedup vs baseline: 1.5778x; 1.5778x over previous
//
#include <hip/hip_runtime.h>

#define NHEAD 16
#define SEQ 2048
#define DMODEL 1024
#define BB 4
#define MROWS (BB*SEQ)      // 8192
#define NBH (BB*NHEAD)      // 64

typedef float f32x4 __attribute__((ext_vector_type(4)));
typedef _Float16 f16x8 __attribute__((ext_vector_type(8)));

static __device__ __forceinline__ f32x4 mfma16(f16x8 a, f16x8 b, f32x4 c) {
  return __builtin_amdgcn_mfma_f32_16x16x32_f16(a, b, c, 0, 0, 0);
}

// fp32 -> f16 hi/lo split: x ~= hi + lo, residual ~2^-22 rel
static __device__ __forceinline__ void split2(float x, unsigned short& hi, unsigned short& lo) {
  _Float16 h = (_Float16)x;
  hi = __builtin_bit_cast(unsigned short, h);
  lo = __builtin_bit_cast(unsigned short, (_Float16)(x - (float)h));
}

// async global->LDS, 16B per lane. lds dest must be the wave-uniform base.
static __device__ __forceinline__ void gload_lds16(const unsigned short* g, unsigned short* l) {
  __builtin_amdgcn_global_load_lds(
      (const __attribute__((address_space(1))) unsigned int*)g,
      (__attribute__((address_space(3))) unsigned int*)l, 16, 0, 0);
}

// ---------------- fp32 -> (hi,lo) f16 split, vectorized ----------------
__global__ __launch_bounds__(256)
void split_f32(const float* __restrict__ src, unsigned short* __restrict__ hi,
               unsigned short* __restrict__ lo, int n4)
{
  int i = blockIdx.x*256 + threadIdx.x;
  const int stride = gridDim.x*256;
  for (; i < n4; i += stride) {
    const float4 x = ((const float4*)src)[i];
    ushort4 h, l;
    split2(x.x, h.x, l.x); split2(x.y, h.y, l.y);
    split2(x.z, h.z, l.z); split2(x.w, h.w, l.w);
    ((ushort4*)hi)[i] = h;
    ((ushort4*)lo)[i] = l;
  }
}

// ---------------- projection GEMM: C = X @ W^T + bias ----------------
// X,W pre-split hi/lo f16 [rows][1024]. Tile 128x128, BK=32.
// LDS row layout (128B): granules 0-3 = hi k0..k0+31, granules 4-7 = lo, XOR-swizzled ^(row&7).
// MODE 0: write hi/lo f16 [B,H,S,64] (Q,K);  MODE 1: f16 V^T [B,H,64,S];  MODE 2: fp32 [M,N]
template<int MODE>
__global__ __launch_bounds__(256, 2)
void proj_gemm(const unsigned short* __restrict__ Xh, const unsigned short* __restrict__ Xl,
               const unsigned short* __restrict__ Wh, const unsigned short* __restrict__ Wl,
               const float* __restrict__ bias,
               unsigned short* __restrict__ o_hi, unsigned short* __restrict__ o_lo,
               float* __restrict__ o_f32)
{
  __shared__ unsigned short As[128][64];
  __shared__ unsigned short Bs[128][64];
  const int tid  = threadIdx.x;
  const int wid  = tid >> 6, lane = tid & 63;
  const int g    = lane >> 4, r16 = lane & 15;
  const int m0   = blockIdx.x * 128, n0 = blockIdx.y * 128;
  const int wr   = wid >> 1, wc = wid & 1;

  f32x4 acc[4][4] = {};

  for (int kt = 0; kt < 32; ++kt) {
    const int k0 = kt*32;
    __syncthreads();
#pragma unroll
    for (int r = 0; r < 4; ++r) {
      const int gi = r*256 + tid;
      const int row = gi >> 3, d = gi & 7;
      const int sg = d ^ (row & 7);
      const unsigned short* sA = (sg < 4)
          ? (Xh + (size_t)(m0+row)*DMODEL + k0 + sg*8)
          : (Xl + (size_t)(m0+row)*DMODEL + k0 + (sg-4)*8);
      const unsigned short* sB = (sg < 4)
          ? (Wh + (size_t)(n0+row)*DMODEL + k0 + sg*8)
          : (Wl + (size_t)(n0+row)*DMODEL + k0 + (sg-4)*8);
      gload_lds16(sA, &As[0][0] + r*2048 + (tid & 0xC0)*8);
      gload_lds16(sB, &Bs[0][0] + r*2048 + (tid & 0xC0)*8);
    }
    asm volatile("s_waitcnt vmcnt(0)" ::: "memory");
    __syncthreads();

    f16x8 a_h[4], a_l[4], b_h[4], b_l[4];
#pragma unroll
    for (int t = 0; t < 4; ++t) {
      const int ar = wr*64 + t*16 + r16;
      const char* pa = (const char*)&As[ar][0];
      a_h[t] = *(const f16x8*)(pa + (((g    ) ^ (ar & 7)) << 4));
      a_l[t] = *(const f16x8*)(pa + (((4 | g) ^ (ar & 7)) << 4));
      const int br = wc*64 + t*16 + r16;
      const char* pb = (const char*)&Bs[br][0];
      b_h[t] = *(const f16x8*)(pb + (((g    ) ^ (br & 7)) << 4));
      b_l[t] = *(const f16x8*)(pb + (((4 | g) ^ (br & 7)) << 4));
    }
#pragma unroll
    for (int mt = 0; mt < 4; ++mt)
#pragma unroll
      for (int nt = 0; nt < 4; ++nt) {
        acc[mt][nt] = mfma16(a_h[mt], b_h[nt], acc[mt][nt]);
        acc[mt][nt] = mfma16(a_h[mt], b_l[nt], acc[mt][nt]);
        acc[mt][nt] = mfma16(a_l[mt], b_h[nt], acc[mt][nt]);
      }
  }

#pragma unroll
  for (int nt = 0; nt < 4; ++nt) {
    const int n  = n0 + wc*64 + nt*16 + r16;
    const float bn = bias[n];
#pragma unroll
    for (int mt = 0; mt < 4; ++mt) {
      const int mb = m0 + wr*64 + mt*16 + g*4;   // C row = 4*(lane>>4)+j
      if (MODE == 0) {
#pragma unroll
        for (int j = 0; j < 4; ++j) {
          const int m = mb + j;
          const float c = acc[mt][nt][j] + bn;
          const int bt = m >> 11, s = m & (SEQ-1);
          const int hh = n >> 6,  d = n & 63;
          const size_t o = (((size_t)(bt*NHEAD + hh)*SEQ + s) << 6) + d;
          unsigned short hi, lo; split2(c, hi, lo);
          o_hi[o] = hi; o_lo[o] = lo;
        }
      } else if (MODE == 1) {
        const int bt = mb >> 11, sb = mb & (SEQ-1);
        const int hh = n >> 6,  d = n & 63;
        ushort4 v;
        v.x = __builtin_bit_cast(unsigned short, (_Float16)(acc[mt][nt][0] + bn));
        v.y = __builtin_bit_cast(unsigned short, (_Float16)(acc[mt][nt][1] + bn));
        v.z = __builtin_bit_cast(unsigned short, (_Float16)(acc[mt][nt][2] + bn));
        v.w = __builtin_bit_cast(unsigned short, (_Float16)(acc[mt][nt][3] + bn));
        *(ushort4*)(o_hi + ((size_t)(bt*NHEAD + hh)*64 + d)*SEQ + sb) = v;
      } else {
#pragma unroll
        for (int j = 0; j < 4; ++j) {
          const int m = mb + j;
          o_f32[(size_t)m*DMODEL + n] = acc[mt][nt][j] + bn;
        }
      }
    }
  }
}

// ---------------- fused attention ----------------
// K tile: Ks[buf][32 keys][128 u16]: granules 0-7 = hi d0..63, 8-15 = lo, swz granule^(row&7)
// V tile: Vs[buf][64 d][32 k u16]: swz granule^(d&3)
static __device__ __forceinline__ void stage_k(unsigned short* dst,
    const unsigned short* __restrict__ Kh, const unsigned short* __restrict__ Kl,
    size_t kbase, int k0, int tid)
{
#pragma unroll
  for (int r = 0; r < 2; ++r) {
    const int gi = r*256 + tid;
    const int row = gi >> 4, dd = gi & 15;
    const int sg = dd ^ (row & 7);
    const unsigned short* src = (sg < 8)
        ? (Kh + kbase + (size_t)(k0+row)*64 + sg*8)
        : (Kl + kbase + (size_t)(k0+row)*64 + (sg-8)*8);
    gload_lds16(src, dst + r*2048 + (tid & 0xC0)*8);
  }
}

static __device__ __forceinline__ void stage_v(unsigned short* dst,
    const unsigned short* __restrict__ Vtg, int bh, int k0, int tid)
{
  const int row = tid >> 2, c = tid & 3;
  const int sg = c ^ (row & 3);
  const unsigned short* src = Vtg + ((size_t)bh*64 + row)*SEQ + k0 + sg*8;
  gload_lds16(src, dst + (tid & 0xC0)*8);
}

__global__ __launch_bounds__(256, 4)
void attn_fused(const unsigned short* __restrict__ Qh, const unsigned short* __restrict__ Ql,
                const unsigned short* __restrict__ Kh, const unsigned short* __restrict__ Kl,
                const unsigned short* __restrict__ Vtg,
                float* __restrict__ wout, float* __restrict__ of32)
{
  __shared__ unsigned short Ks[2][32][128];
  __shared__ unsigned short Vs[2][64][32];
  __shared__ unsigned short PA[4][16][32];
  const int tid = threadIdx.x, wid = tid >> 6, lane = tid & 63;
  const int g = lane >> 4, r16 = lane & 15;
  const int bh = blockIdx.y, bt = bh >> 4, hh = bh & (NHEAD-1);
  const int s0 = blockIdx.x*64 + wid*16;
  const size_t kbase = (size_t)bh*SEQ*64;

  const size_t qoff = ((size_t)bh*SEQ + s0 + r16)*64 + (size_t)g*8;
  const f16x8 qh0 = *(const f16x8*)(Qh + qoff);
  const f16x8 qh1 = *(const f16x8*)(Qh + qoff + 32);
  const f16x8 ql0 = *(const f16x8*)(Ql + qoff);
  const f16x8 ql1 = *(const f16x8*)(Ql + qoff + 32);

  float mr[4] = {-1e30f, -1e30f, -1e30f, -1e30f};
  float lp[4] = {0.f, 0.f, 0.f, 0.f};

  // ---- pass 1: online m, l ----
  stage_k(&Ks[0][0][0], Kh, Kl, kbase, 0, tid);
  asm volatile("s_waitcnt vmcnt(0)" ::: "memory");
  __syncthreads();
  for (int kt = 0; kt < SEQ/32; ++kt) {
    const int cur = kt & 1;
    if (kt < SEQ/32 - 1) stage_k(&Ks[cur^1][0][0], Kh, Kl, kbase, (kt+1)*32, tid);
#pragma unroll
    for (int sub = 0; sub < 2; ++sub) {
      const int krow = sub*16 + r16;
      const char* pk = (const char*)&Ks[cur][krow][0];
      const int sx = krow & 7;
      const f16x8 kh0 = *(const f16x8*)(pk + (((g     ) ^ sx) << 4));
      const f16x8 kh1 = *(const f16x8*)(pk + ((( 4 | g) ^ sx) << 4));
      const f16x8 kl0 = *(const f16x8*)(pk + ((( 8 | g) ^ sx) << 4));
      const f16x8 kl1 = *(const f16x8*)(pk + (((12 | g) ^ sx) << 4));
      f32x4 acc = {};
      acc = mfma16(qh0, kh0, acc); acc = mfma16(qh1, kh1, acc);
      acc = mfma16(qh0, kl0, acc); acc = mfma16(qh1, kl1, acc);
      acc = mfma16(ql0, kh0, acc); acc = mfma16(ql1, kh1, acc);
#pragma unroll
      for (int j = 0; j < 4; ++j) {
        const float sc = acc[j] * 0.125f;
        float tm = sc;
        tm = fmaxf(tm, __shfl_xor(tm, 1));
        tm = fmaxf(tm, __shfl_xor(tm, 2));
        tm = fmaxf(tm, __shfl_xor(tm, 4));
        tm = fmaxf(tm, __shfl_xor(tm, 8));
        const float mn = fmaxf(mr[j], tm);
        lp[j] = lp[j] * __expf(mr[j] - mn) + __expf(sc - mn);
        mr[j] = mn;
      }
    }
    asm volatile("s_waitcnt vmcnt(0)" ::: "memory");
    __syncthreads();
  }

  float mj[4], li[4];
#pragma unroll
  for (int j = 0; j < 4; ++j) {
    float l = lp[j];
    l += __shfl_xor(l, 1);
    l += __shfl_xor(l, 2);
    l += __shfl_xor(l, 4);
    l += __shfl_xor(l, 8);
    mj[j] = mr[j];
    li[j] = 1.0f / l;
  }

  // ---- pass 2: weights + PV ----
  f32x4 acco[4] = {};
  float* wb = wout + ((size_t)bh*SEQ + s0)*SEQ;

  stage_k(&Ks[0][0][0], Kh, Kl, kbase, 0, tid);
  stage_v(&Vs[0][0][0], Vtg, bh, 0, tid);
  asm volatile("s_waitcnt vmcnt(0)" ::: "memory");
  __syncthreads();
  for (int kt = 0; kt < SEQ/32; ++kt) {
    const int cur = kt & 1;
    if (kt < SEQ/32 - 1) {
      stage_k(&Ks[cur^1][0][0], Kh, Kl, kbase, (kt+1)*32, tid);
      stage_v(&Vs[cur^1][0][0], Vtg, bh, (kt+1)*32, tid);
    }
#pragma unroll
    for (int sub = 0; sub < 2; ++sub) {
      const int krow = sub*16 + r16;
      const char* pk = (const char*)&Ks[cur][krow][0];
      const int sx = krow & 7;
      const f16x8 kh0 = *(const f16x8*)(pk + (((g     ) ^ sx) << 4));
      const f16x8 kh1 = *(const f16x8*)(pk + ((( 4 | g) ^ sx) << 4));
      const f16x8 kl0 = *(const f16x8*)(pk + ((( 8 | g) ^ sx) << 4));
      const f16x8 kl1 = *(const f16x8*)(pk + (((12 | g) ^ sx) << 4));
      f32x4 acc = {};
      acc = mfma16(qh0, kh0, acc); acc = mfma16(qh1, kh1, acc);
      acc = mfma16(qh0, kl0, acc); acc = mfma16(qh1, kl1, acc);
      acc = mfma16(ql0, kh0, acc); acc = mfma16(ql1, kh1, acc);
#pragma unroll
      for (int j = 0; j < 4; ++j) {
        const float w = __expf(acc[j]*0.125f - mj[j]) * li[j];
        wb[(size_t)(g*4 + j)*SEQ + kt*32 + sub*16 + r16] = w;
        const int q = g*4 + j;
        const int gr = (sub*2 + (r16 >> 3)) ^ (q & 3);
        *(unsigned short*)((char*)&PA[wid][q][0] + (gr << 4) + (r16 & 7)*2) =
            __builtin_bit_cast(unsigned short, (_Float16)w);
      }
    }
    asm volatile("s_waitcnt lgkmcnt(0)" ::: "memory");
    const char* pp = (const char*)&PA[wid][r16][0];
    const f16x8 pa = *(const f16x8*)(pp + ((g ^ (r16 & 3)) << 4));
#pragma unroll
    for (int nt = 0; nt < 4; ++nt) {
      const int vrow = nt*16 + r16;
      const char* pv = (const char*)&Vs[cur][vrow][0];
      const f16x8 vv = *(const f16x8*)(pv + ((g ^ (vrow & 3)) << 4));
      acco[nt] = mfma16(pa, vv, acco[nt]);
    }
    asm volatile("s_waitcnt vmcnt(0)" ::: "memory");
    __syncthreads();
  }

#pragma unroll
  for (int nt = 0; nt < 4; ++nt)
#pragma unroll
    for (int j = 0; j < 4; ++j)
      of32[((size_t)bt*SEQ + s0 + g*4 + j)*DMODEL + hh*64 + nt*16 + r16] = acco[nt][j];
}

extern "C" void kernel_launch(void* const* d_in, const int* in_sizes, int n_in,
                              void* d_out, int out_size, void* d_ws, size_t ws_size,
                              hipStream_t stream)
{
  const float* query = (const float*)d_in[0];
  const float* key_  = (const float*)d_in[1];
  const float* value = (const float*)d_in[2];
  const float* Wq = (const float*)d_in[3];
  const float* bq = (const float*)d_in[4];
  const float* Wk = (const float*)d_in[5];
  const float* bk = (const float*)d_in[6];
  const float* Wv = (const float*)d_in[7];
  const float* bv = (const float*)d_in[8];
  const float* Wo = (const float*)d_in[9];
  const float* bo = (const float*)d_in[10];

  // workspace layout (~122 MB)
  const size_t NE = (size_t)NBH * SEQ * 64;        // 8,388,608
  unsigned short* Qh = (unsigned short*)d_ws;      // after attn reused as Of-split hi
  unsigned short* Ql = Qh + NE;                    // after attn reused as Of-split lo
  unsigned short* Kh = Ql + NE;
  unsigned short* Kl = Kh + NE;
  unsigned short* Vt = Kl + NE;                    // f16 V^T [B,H,64,S]
  unsigned short* SH = Vt + NE;                    // X-split hi (8192x1024)
  unsigned short* SL = SH + (size_t)MROWS*DMODEL;  // X-split lo
  unsigned short* WH = SL + (size_t)MROWS*DMODEL;  // W-split hi (1024x1024)
  unsigned short* WL = WH + (size_t)DMODEL*DMODEL; // W-split lo
  float* Of = (float*)SH;                          // attn out [M,D] overlays SH+SL (X splits dead)

  float* out0  = (float*)d_out;
  float* wattn = out0 + (size_t)MROWS * DMODEL;    // attention weights [B,H,S,S]

  const int nX4 = MROWS*DMODEL/4, nW4 = DMODEL*DMODEL/4;
  dim3 gg(MROWS/128, DMODEL/128);

  split_f32<<<2048, 256, 0, stream>>>(query, SH, SL, nX4);
  split_f32<<<512,  256, 0, stream>>>(Wq, WH, WL, nW4);
  proj_gemm<0><<<gg, dim3(256), 0, stream>>>(SH, SL, WH, WL, bq, Qh, Ql, nullptr);

  split_f32<<<2048, 256, 0, stream>>>(key_, SH, SL, nX4);
  split_f32<<<512,  256, 0, stream>>>(Wk, WH, WL, nW4);
  proj_gemm<0><<<gg, dim3(256), 0, stream>>>(SH, SL, WH, WL, bk, Kh, Kl, nullptr);

  split_f32<<<2048, 256, 0, stream>>>(value, SH, SL, nX4);
  split_f32<<<512,  256, 0, stream>>>(Wv, WH, WL, nW4);
  proj_gemm<1><<<gg, dim3(256), 0, stream>>>(SH, SL, WH, WL, bv, Vt, nullptr, nullptr);

  attn_fused<<<dim3(SEQ/64, NBH), dim3(256), 0, stream>>>(Qh, Ql, Kh, Kl, Vt, wattn, Of);

  split_f32<<<2048, 256, 0, stream>>>(Of, Qh, Ql, nX4);   // reuse Qh/Ql as Of-split
  split_f32<<<512,  256, 0, stream>>>(Wo, WH, WL, nW4);
  proj_gemm<2><<<gg, dim3(256), 0, stream>>>(Qh, Ql, WH, WL, bo, nullptr, nullptr, out0);
}

// Round 3
// 590.792 us; speedup vs baseline: 2.6072x; 1.6524x over previous
//
#include <hip/hip_runtime.h>

#define NHEAD 16
#define SEQ 2048
#define DMODEL 1024
#define BB 4
#define MROWS (BB*SEQ)      // 8192
#define NBH (BB*NHEAD)      // 64
#define NT (SEQ/32)         // 64 k-tiles

typedef float f32x4 __attribute__((ext_vector_type(4)));
typedef _Float16 f16x8 __attribute__((ext_vector_type(8)));
typedef _Float16 f16x4 __attribute__((ext_vector_type(4)));

static __device__ __forceinline__ f32x4 mfma16(f16x8 a, f16x8 b, f32x4 c) {
  return __builtin_amdgcn_mfma_f32_16x16x32_f16(a, b, c, 0, 0, 0);
}

static __device__ __forceinline__ void split2(float x, unsigned short& hi, unsigned short& lo) {
  _Float16 h = (_Float16)x;
  hi = __builtin_bit_cast(unsigned short, h);
  lo = __builtin_bit_cast(unsigned short, (_Float16)(x - (float)h));
}

static __device__ __forceinline__ void gload_lds16(const unsigned short* g, unsigned short* l) {
  __builtin_amdgcn_global_load_lds(
      (const __attribute__((address_space(1))) unsigned int*)g,
      (__attribute__((address_space(3))) unsigned int*)l, 16, 0, 0);
}

// fp32 -> f16 round (activations)
__global__ __launch_bounds__(256)
void round_f16(const float* __restrict__ src, unsigned short* __restrict__ dst, int n4)
{
  int i = blockIdx.x*256 + threadIdx.x;
  const int stride = gridDim.x*256;
  for (; i < n4; i += stride) {
    const float4 x = ((const float4*)src)[i];
    ushort4 h;
    h.x = __builtin_bit_cast(unsigned short, (_Float16)x.x);
    h.y = __builtin_bit_cast(unsigned short, (_Float16)x.y);
    h.z = __builtin_bit_cast(unsigned short, (_Float16)x.z);
    h.w = __builtin_bit_cast(unsigned short, (_Float16)x.w);
    ((ushort4*)dst)[i] = h;
  }
}

// fp32 -> hi/lo split (weights only)
__global__ __launch_bounds__(256)
void split_f32(const float* __restrict__ src, unsigned short* __restrict__ hi,
               unsigned short* __restrict__ lo, int n4)
{
  int i = blockIdx.x*256 + threadIdx.x;
  const int stride = gridDim.x*256;
  for (; i < n4; i += stride) {
    const float4 x = ((const float4*)src)[i];
    ushort4 h, l;
    split2(x.x, h.x, l.x); split2(x.y, h.y, l.y);
    split2(x.z, h.z, l.z); split2(x.w, h.w, l.w);
    ((ushort4*)hi)[i] = h;
    ((ushort4*)lo)[i] = l;
  }
}

// ---------------- projection GEMM: C = X @ W^T + bias ----------------
// X f16 [8192][1024]; W hi/lo f16 [1024][1024]. Tile 128x128, BK=32, 32 MFMA/kt.
// MODE 0: f16 [B,H,S,64];  MODE 1: f16 V^T [B,H,64,S];  MODE 2: fp32 [M,N]
template<int MODE>
__global__ __launch_bounds__(256, 2)
void proj_gemm(const unsigned short* __restrict__ Xf,
               const unsigned short* __restrict__ Wh, const unsigned short* __restrict__ Wl,
               const float* __restrict__ bias,
               unsigned short* __restrict__ o16, float* __restrict__ o_f32)
{
  __shared__ unsigned short As[128][32];   // rows 64B = 4 granules, swz ^((row>>1)&3)
  __shared__ unsigned short Bs[128][64];   // rows 128B: gran 0-3 hi, 4-7 lo, swz ^(row&7)
  const int tid  = threadIdx.x;
  const int wid  = tid >> 6, lane = tid & 63;
  const int g    = lane >> 4, r16 = lane & 15;
  // XCD swizzle: 512 blocks -> 8 m-tile slab per XCD, n outer
  const int id   = blockIdx.y*64 + blockIdx.x;
  const int xcd  = id & 7, slot = id >> 3;
  const int m0   = (xcd*8 + (slot & 7)) * 128;
  const int n0   = (slot >> 3) * 128;
  const int wr   = wid >> 1, wc = wid & 1;

  f32x4 acc[4][4] = {};

  for (int kt = 0; kt < 32; ++kt) {
    const int k0 = kt*32;
    __syncthreads();
#pragma unroll
    for (int r = 0; r < 2; ++r) {            // A: 8KB
      const int gi = r*256 + tid;
      const int row = gi >> 2, c = gi & 3;
      const int lg = c ^ ((row >> 1) & 3);
      gload_lds16(Xf + (size_t)(m0+row)*DMODEL + k0 + lg*8,
                  &As[0][0] + r*2048 + (tid & 0xC0)*8);
    }
#pragma unroll
    for (int r = 0; r < 4; ++r) {            // B: 16KB
      const int gi = r*256 + tid;
      const int row = gi >> 3, c = gi & 7;
      const int sg = c ^ (row & 7);
      const unsigned short* src = (sg < 4)
          ? (Wh + (size_t)(n0+row)*DMODEL + k0 + sg*8)
          : (Wl + (size_t)(n0+row)*DMODEL + k0 + (sg-4)*8);
      gload_lds16(src, &Bs[0][0] + r*2048 + (tid & 0xC0)*8);
    }
    asm volatile("s_waitcnt vmcnt(0)" ::: "memory");
    __syncthreads();

    f16x8 a[4], b_h[4], b_l[4];
#pragma unroll
    for (int t = 0; t < 4; ++t) {
      const int ar = wr*64 + t*16 + r16;
      a[t] = *(const f16x8*)((const char*)&As[ar][0] + ((g ^ ((ar >> 1) & 3)) << 4));
      const int br = wc*64 + t*16 + r16;
      const char* pb = (const char*)&Bs[br][0];
      b_h[t] = *(const f16x8*)(pb + (((g    ) ^ (br & 7)) << 4));
      b_l[t] = *(const f16x8*)(pb + (((4 | g) ^ (br & 7)) << 4));
    }
#pragma unroll
    for (int mt = 0; mt < 4; ++mt)
#pragma unroll
      for (int nt = 0; nt < 4; ++nt) {
        acc[mt][nt] = mfma16(a[mt], b_h[nt], acc[mt][nt]);
        acc[mt][nt] = mfma16(a[mt], b_l[nt], acc[mt][nt]);
      }
  }

#pragma unroll
  for (int nt = 0; nt < 4; ++nt) {
    const int n  = n0 + wc*64 + nt*16 + r16;
    const float bn = bias[n];
#pragma unroll
    for (int mt = 0; mt < 4; ++mt) {
      const int mb = m0 + wr*64 + mt*16 + g*4;
      if (MODE == 0) {
#pragma unroll
        for (int j = 0; j < 4; ++j) {
          const int m = mb + j;
          const int bt = m >> 11, s = m & (SEQ-1);
          const int hh = n >> 6,  d = n & 63;
          o16[(((size_t)(bt*NHEAD + hh)*SEQ + s) << 6) + d] =
              __builtin_bit_cast(unsigned short, (_Float16)(acc[mt][nt][j] + bn));
        }
      } else if (MODE == 1) {
        const int bt = mb >> 11, sb = mb & (SEQ-1);
        const int hh = n >> 6,  d = n & 63;
        ushort4 v;
        v.x = __builtin_bit_cast(unsigned short, (_Float16)(acc[mt][nt][0] + bn));
        v.y = __builtin_bit_cast(unsigned short, (_Float16)(acc[mt][nt][1] + bn));
        v.z = __builtin_bit_cast(unsigned short, (_Float16)(acc[mt][nt][2] + bn));
        v.w = __builtin_bit_cast(unsigned short, (_Float16)(acc[mt][nt][3] + bn));
        *(ushort4*)(o16 + ((size_t)(bt*NHEAD + hh)*64 + d)*SEQ + sb) = v;
      } else {
#pragma unroll
        for (int j = 0; j < 4; ++j)
          o_f32[(size_t)(mb + j)*DMODEL + n] = acc[mt][nt][j] + bn;
      }
    }
  }
}

// ---------------- fused attention ----------------
// Ks[buf][32 k][64 u16]: rows 128B, granule 0-7 = d-chunks, swz ^(row&7)
// Vs[buf][64 d][32 u16]: rows 64B, granule 0-3 = k-chunks, swz ^((row>>1)&3)
// PA[wave][16 q][40 u16]: rows 80B, granule 0-3 = k-chunks, swz ^(q&3)
static __device__ __forceinline__ void stage_k(unsigned short* dst,
    const unsigned short* __restrict__ Kf, size_t kbase, int k0, int tid)
{
  const int row = tid >> 3, c = tid & 7;
  const int sg = c ^ (row & 7);
  gload_lds16(Kf + kbase + (size_t)(k0+row)*64 + sg*8, dst + (tid & 0xC0)*8);
}

static __device__ __forceinline__ void stage_v(unsigned short* dst,
    const unsigned short* __restrict__ Vtg, int bh, int k0, int tid)
{
  const int row = tid >> 2, c = tid & 3;
  const int lg = c ^ ((row >> 1) & 3);
  gload_lds16(Vtg + ((size_t)bh*64 + row)*SEQ + k0 + lg*8, dst + (tid & 0xC0)*8);
}

__global__ __launch_bounds__(256, 4)
void attn_fused(const unsigned short* __restrict__ Qf, const unsigned short* __restrict__ Kf,
                const unsigned short* __restrict__ Vtg,
                float* __restrict__ wout, unsigned short* __restrict__ of16)
{
  __shared__ unsigned short Ks[2][32][64];
  __shared__ unsigned short Vs[2][64][32];
  __shared__ unsigned short PA[4][16][40];
  const int tid = threadIdx.x, wid = tid >> 6, lane = tid & 63;
  const int g = lane >> 4, r16 = lane & 15;
  // XCD swizzle: all 32 q-blocks of one bh on the same XCD
  const int id = blockIdx.y*32 + blockIdx.x;
  const int xcd = id & 7, slot = id >> 3;
  const int bh = (slot >> 5)*8 + xcd;
  const int bx = slot & 31;
  const int bt = bh >> 4, hh = bh & (NHEAD-1);
  const int s0 = bx*64 + wid*16;
  const size_t kbase = (size_t)bh*SEQ*64;

  const size_t qoff = ((size_t)bh*SEQ + s0 + r16)*64 + (size_t)g*8;
  const f16x8 qh0 = *(const f16x8*)(Qf + qoff);
  const f16x8 qh1 = *(const f16x8*)(Qf + qoff + 32);

  // ---- pass 1: m (deferred max), l ----
  float mr = -1e30f, lp = 0.f;
  stage_k(&Ks[0][0][0], Kf, kbase, 0, tid);
  asm volatile("s_waitcnt vmcnt(0)" ::: "memory");
  __syncthreads();
  for (int kt = 0; kt < NT; ++kt) {
    const int cur = kt & 1;
    if (kt < NT-1) stage_k(&Ks[cur^1][0][0], Kf, kbase, (kt+1)*32, tid);
    float sc[8];
#pragma unroll
    for (int sub = 0; sub < 2; ++sub) {
      const int krow = sub*16 + r16;
      const char* pk = (const char*)&Ks[cur][krow][0];
      const int sx = krow & 7;
      const f16x8 kh0 = *(const f16x8*)(pk + (((g    ) ^ sx) << 4));
      const f16x8 kh1 = *(const f16x8*)(pk + (((4 | g) ^ sx) << 4));
      f32x4 acc = {};
      acc = mfma16(kh0, qh0, acc);
      acc = mfma16(kh1, qh1, acc);
#pragma unroll
      for (int j = 0; j < 4; ++j) sc[sub*4+j] = acc[j] * 0.125f;
    }
    float m8 = sc[0];
#pragma unroll
    for (int i = 1; i < 8; ++i) m8 = fmaxf(m8, sc[i]);
    if (!__all(m8 <= mr + 8.f)) {
      float tm = m8;
      tm = fmaxf(tm, __shfl_xor(tm, 16));
      tm = fmaxf(tm, __shfl_xor(tm, 32));
      const float mn = fmaxf(mr, tm);
      lp *= __expf(mr - mn);
      mr = mn;
    }
#pragma unroll
    for (int i = 0; i < 8; ++i) lp += __expf(sc[i] - mr);
    asm volatile("s_waitcnt vmcnt(0)" ::: "memory");
    __syncthreads();
  }
  lp += __shfl_xor(lp, 16);
  lp += __shfl_xor(lp, 32);
  const float li = 1.0f / lp;

  // ---- pass 2: weights + PV ----
  f32x4 acco[4] = {};
  char* paw = (char*)&PA[wid][0][0];

  stage_k(&Ks[0][0][0], Kf, kbase, 0, tid);
  stage_v(&Vs[0][0][0], Vtg, bh, 0, tid);
  asm volatile("s_waitcnt vmcnt(0)" ::: "memory");
  __syncthreads();
  for (int kt = 0; kt < NT; ++kt) {
    const int cur = kt & 1;
    if (kt < NT-1) {
      stage_k(&Ks[cur^1][0][0], Kf, kbase, (kt+1)*32, tid);
      stage_v(&Vs[cur^1][0][0], Vtg, bh, (kt+1)*32, tid);
    }
#pragma unroll
    for (int sub = 0; sub < 2; ++sub) {
      const int krow = sub*16 + r16;
      const char* pk = (const char*)&Ks[cur][krow][0];
      const int sx = krow & 7;
      const f16x8 kh0 = *(const f16x8*)(pk + (((g    ) ^ sx) << 4));
      const f16x8 kh1 = *(const f16x8*)(pk + (((4 | g) ^ sx) << 4));
      f32x4 acc = {};
      acc = mfma16(kh0, qh0, acc);
      acc = mfma16(kh1, qh1, acc);
      f32x4 w4;
      f16x4 p4;
#pragma unroll
      for (int j = 0; j < 4; ++j) {
        w4[j] = __expf(acc[j]*0.125f - mr) * li;
        p4[j] = (_Float16)w4[j];
      }
      // weights: one nontemporal 16B store (q = s0+r16, k = kt*32+sub*16+4g+j)
      float* wp = wout + ((size_t)bh*SEQ + s0 + r16)*SEQ + kt*32 + sub*16 + 4*g;
      __builtin_nontemporal_store(w4, (f32x4*)wp);
      // PA: q=r16 row, k-granule G = 2sub+(g>>1), swz ^(r16&3), half (g&1)
      *(f16x4*)(paw + r16*80 + ((((2*sub + (g >> 1)) ^ (r16 & 3)) << 4) | ((g & 1) << 3))) = p4;
    }
    asm volatile("s_waitcnt lgkmcnt(0)" ::: "memory");
    const f16x8 pa = *(const f16x8*)(paw + r16*80 + ((g ^ (r16 & 3)) << 4));
#pragma unroll
    for (int nt = 0; nt < 4; ++nt) {
      const int vrow = nt*16 + r16;
      const f16x8 vv = *(const f16x8*)((const char*)&Vs[cur][vrow][0] +
                                       ((g ^ ((vrow >> 1) & 3)) << 4));
      acco[nt] = mfma16(pa, vv, acco[nt]);
    }
    asm volatile("s_waitcnt vmcnt(0)" ::: "memory");
    __syncthreads();
  }

  // O rows q = s0 + 4g + j, col d = hh*64 + nt*16 + r16, f16
#pragma unroll
  for (int nt = 0; nt < 4; ++nt)
#pragma unroll
    for (int j = 0; j < 4; ++j)
      of16[((size_t)bt*SEQ + s0 + 4*g + j)*DMODEL + hh*64 + nt*16 + r16] =
          __builtin_bit_cast(unsigned short, (_Float16)acco[nt][j]);
}

extern "C" void kernel_launch(void* const* d_in, const int* in_sizes, int n_in,
                              void* d_out, int out_size, void* d_ws, size_t ws_size,
                              hipStream_t stream)
{
  const float* query = (const float*)d_in[0];
  const float* key_  = (const float*)d_in[1];
  const float* value = (const float*)d_in[2];
  const float* Wq = (const float*)d_in[3];
  const float* bq = (const float*)d_in[4];
  const float* Wk = (const float*)d_in[5];
  const float* bk = (const float*)d_in[6];
  const float* Wv = (const float*)d_in[7];
  const float* bv = (const float*)d_in[8];
  const float* Wo = (const float*)d_in[9];
  const float* bo = (const float*)d_in[10];

  const size_t NE = (size_t)NBH * SEQ * 64;        // 8,388,608
  unsigned short* X16 = (unsigned short*)d_ws;     // activation f16 (reused)
  unsigned short* Qf  = X16 + NE;
  unsigned short* Kf  = Qf + NE;
  unsigned short* Vt  = Kf + NE;                   // V^T [B,H,64,S]
  unsigned short* Of  = Vt + NE;                   // attn out f16 [M][D]
  unsigned short* WH  = Of + NE;
  unsigned short* WL  = WH + (size_t)DMODEL*DMODEL;

  float* out0  = (float*)d_out;
  float* wattn = out0 + (size_t)MROWS * DMODEL;

  const int nX4 = MROWS*DMODEL/4, nW4 = DMODEL*DMODEL/4;
  dim3 gg(64, 8);

  round_f16<<<1024, 256, 0, stream>>>(query, X16, nX4);
  split_f32<<<512,  256, 0, stream>>>(Wq, WH, WL, nW4);
  proj_gemm<0><<<gg, dim3(256), 0, stream>>>(X16, WH, WL, bq, Qf, nullptr);

  round_f16<<<1024, 256, 0, stream>>>(key_, X16, nX4);
  split_f32<<<512,  256, 0, stream>>>(Wk, WH, WL, nW4);
  proj_gemm<0><<<gg, dim3(256), 0, stream>>>(X16, WH, WL, bk, Kf, nullptr);

  round_f16<<<1024, 256, 0, stream>>>(value, X16, nX4);
  split_f32<<<512,  256, 0, stream>>>(Wv, WH, WL, nW4);
  proj_gemm<1><<<gg, dim3(256), 0, stream>>>(X16, WH, WL, bv, Vt, nullptr);

  attn_fused<<<dim3(32, NBH), dim3(256), 0, stream>>>(Qf, Kf, Vt, wattn, Of);

  split_f32<<<512,  256, 0, stream>>>(Wo, WH, WL, nW4);
  proj_gemm<2><<<gg, dim3(256), 0, stream>>>(Of, WH, WL, bo, nullptr, out0);
}

// Round 4
// 554.544 us; speedup vs baseline: 2.7776x; 1.0654x over previous
//
#include <hip/hip_runtime.h>

#define NHEAD 16
#define SEQ 2048
#define DMODEL 1024
#define BB 4
#define MROWS (BB*SEQ)      // 8192
#define NBH (BB*NHEAD)      // 64
#define NT (SEQ/32)         // 64 k-tiles

typedef float f32x4 __attribute__((ext_vector_type(4)));
typedef _Float16 f16x8 __attribute__((ext_vector_type(8)));
typedef _Float16 f16x4 __attribute__((ext_vector_type(4)));

static __device__ __forceinline__ f32x4 mfma16(f16x8 a, f16x8 b, f32x4 c) {
  return __builtin_amdgcn_mfma_f32_16x16x32_f16(a, b, c, 0, 0, 0);
}

static __device__ __forceinline__ void split2(float x, unsigned short& hi, unsigned short& lo) {
  _Float16 h = (_Float16)x;
  hi = __builtin_bit_cast(unsigned short, h);
  lo = __builtin_bit_cast(unsigned short, (_Float16)(x - (float)h));
}

static __device__ __forceinline__ void gload_lds16(const unsigned short* g, unsigned short* l) {
  __builtin_amdgcn_global_load_lds(
      (const __attribute__((address_space(1))) unsigned int*)g,
      (__attribute__((address_space(3))) unsigned int*)l, 16, 0, 0);
}

// fp32 -> f16 round (activations)
__global__ __launch_bounds__(256)
void round_f16(const float* __restrict__ src, unsigned short* __restrict__ dst, int n4)
{
  int i = blockIdx.x*256 + threadIdx.x;
  const int stride = gridDim.x*256;
  for (; i < n4; i += stride) {
    const float4 x = ((const float4*)src)[i];
    ushort4 h;
    h.x = __builtin_bit_cast(unsigned short, (_Float16)x.x);
    h.y = __builtin_bit_cast(unsigned short, (_Float16)x.y);
    h.z = __builtin_bit_cast(unsigned short, (_Float16)x.z);
    h.w = __builtin_bit_cast(unsigned short, (_Float16)x.w);
    ((ushort4*)dst)[i] = h;
  }
}

// fp32 -> hi/lo split (weights only)
__global__ __launch_bounds__(256)
void split_f32(const float* __restrict__ src, unsigned short* __restrict__ hi,
               unsigned short* __restrict__ lo, int n4)
{
  int i = blockIdx.x*256 + threadIdx.x;
  const int stride = gridDim.x*256;
  for (; i < n4; i += stride) {
    const float4 x = ((const float4*)src)[i];
    ushort4 h, l;
    split2(x.x, h.x, l.x); split2(x.y, h.y, l.y);
    split2(x.z, h.z, l.z); split2(x.w, h.w, l.w);
    ((ushort4*)hi)[i] = h;
    ((ushort4*)lo)[i] = l;
  }
}

// ---------------- projection GEMM: C = (X @ W^T + bias) * oscale ----------------
// X f16 [8192][1024]; W hi/lo f16 [1024][1024]. Tile 128x128, BK=32, 32 MFMA/kt.
// MODE 0: f16 [B,H,S,64] scaled;  MODE 1: f16 V^T [B,H,64,S];  MODE 2: fp32 [M,N]
template<int MODE>
__global__ __launch_bounds__(256, 2)
void proj_gemm(const unsigned short* __restrict__ Xf,
               const unsigned short* __restrict__ Wh, const unsigned short* __restrict__ Wl,
               const float* __restrict__ bias, float oscale,
               unsigned short* __restrict__ o16, float* __restrict__ o_f32)
{
  __shared__ unsigned short As[128][32];   // rows 64B = 4 granules, swz ^((row>>1)&3)
  __shared__ unsigned short Bs[128][64];   // rows 128B: gran 0-3 hi, 4-7 lo, swz ^(row&7)
  const int tid  = threadIdx.x;
  const int wid  = tid >> 6, lane = tid & 63;
  const int g    = lane >> 4, r16 = lane & 15;
  const int id   = blockIdx.y*64 + blockIdx.x;
  const int xcd  = id & 7, slot = id >> 3;
  const int m0   = (xcd*8 + (slot & 7)) * 128;
  const int n0   = (slot >> 3) * 128;
  const int wr   = wid >> 1, wc = wid & 1;

  f32x4 acc[4][4] = {};

  for (int kt = 0; kt < 32; ++kt) {
    const int k0 = kt*32;
    __syncthreads();
#pragma unroll
    for (int r = 0; r < 2; ++r) {            // A: 8KB
      const int gi = r*256 + tid;
      const int row = gi >> 2, c = gi & 3;
      const int lg = c ^ ((row >> 1) & 3);
      gload_lds16(Xf + (size_t)(m0+row)*DMODEL + k0 + lg*8,
                  &As[0][0] + r*2048 + (tid & 0xC0)*8);
    }
#pragma unroll
    for (int r = 0; r < 4; ++r) {            // B: 16KB
      const int gi = r*256 + tid;
      const int row = gi >> 3, c = gi & 7;
      const int sg = c ^ (row & 7);
      const unsigned short* src = (sg < 4)
          ? (Wh + (size_t)(n0+row)*DMODEL + k0 + sg*8)
          : (Wl + (size_t)(n0+row)*DMODEL + k0 + (sg-4)*8);
      gload_lds16(src, &Bs[0][0] + r*2048 + (tid & 0xC0)*8);
    }
    asm volatile("s_waitcnt vmcnt(0)" ::: "memory");
    __syncthreads();

    f16x8 a[4], b_h[4], b_l[4];
#pragma unroll
    for (int t = 0; t < 4; ++t) {
      const int ar = wr*64 + t*16 + r16;
      a[t] = *(const f16x8*)((const char*)&As[ar][0] + ((g ^ ((ar >> 1) & 3)) << 4));
      const int br = wc*64 + t*16 + r16;
      const char* pb = (const char*)&Bs[br][0];
      b_h[t] = *(const f16x8*)(pb + (((g    ) ^ (br & 7)) << 4));
      b_l[t] = *(const f16x8*)(pb + (((4 | g) ^ (br & 7)) << 4));
    }
#pragma unroll
    for (int mt = 0; mt < 4; ++mt)
#pragma unroll
      for (int nt = 0; nt < 4; ++nt) {
        acc[mt][nt] = mfma16(a[mt], b_h[nt], acc[mt][nt]);
        acc[mt][nt] = mfma16(a[mt], b_l[nt], acc[mt][nt]);
      }
  }

#pragma unroll
  for (int nt = 0; nt < 4; ++nt) {
    const int n  = n0 + wc*64 + nt*16 + r16;
    const float bn = bias[n];
#pragma unroll
    for (int mt = 0; mt < 4; ++mt) {
      const int mb = m0 + wr*64 + mt*16 + g*4;
      if (MODE == 0) {
#pragma unroll
        for (int j = 0; j < 4; ++j) {
          const int m = mb + j;
          const int bt = m >> 11, s = m & (SEQ-1);
          const int hh = n >> 6,  d = n & 63;
          o16[(((size_t)(bt*NHEAD + hh)*SEQ + s) << 6) + d] =
              __builtin_bit_cast(unsigned short, (_Float16)((acc[mt][nt][j] + bn) * oscale));
        }
      } else if (MODE == 1) {
        const int bt = mb >> 11, sb = mb & (SEQ-1);
        const int hh = n >> 6,  d = n & 63;
        ushort4 v;
        v.x = __builtin_bit_cast(unsigned short, (_Float16)(acc[mt][nt][0] + bn));
        v.y = __builtin_bit_cast(unsigned short, (_Float16)(acc[mt][nt][1] + bn));
        v.z = __builtin_bit_cast(unsigned short, (_Float16)(acc[mt][nt][2] + bn));
        v.w = __builtin_bit_cast(unsigned short, (_Float16)(acc[mt][nt][3] + bn));
        *(ushort4*)(o16 + ((size_t)(bt*NHEAD + hh)*64 + d)*SEQ + sb) = v;
      } else {
#pragma unroll
        for (int j = 0; j < 4; ++j)
          o_f32[(size_t)(mb + j)*DMODEL + n] = acc[mt][nt][j] + bn;
      }
    }
  }
}

// ---------------- fused attention ----------------
// Ks[buf][32 k][64 u16]: rows 128B, granule 0-7 = d-chunks, swz ^(row&7)
// Vs[buf][64 d][32 u16]: rows 64B, granule 0-3 = k-chunks, swz ^((row>>1)&3)
// PA[wave][16 q][40 u16]: rows 80B, granule 0-3 = k-chunks, swz ^(q&3)
static __device__ __forceinline__ void stage_k(unsigned short* dst,
    const unsigned short* __restrict__ Kf, size_t kbase, int k0, int tid)
{
  const int row = tid >> 3, c = tid & 7;
  const int sg = c ^ (row & 7);
  gload_lds16(Kf + kbase + (size_t)(k0+row)*64 + sg*8, dst + (tid & 0xC0)*8);
}

static __device__ __forceinline__ void stage_v(unsigned short* dst,
    const unsigned short* __restrict__ Vtg, int bh, int k0, int tid)
{
  const int row = tid >> 2, c = tid & 3;
  const int lg = c ^ ((row >> 1) & 3);
  gload_lds16(Vtg + ((size_t)bh*64 + row)*SEQ + k0 + lg*8, dst + (tid & 0xC0)*8);
}

__global__ __launch_bounds__(256, 4)
void attn_fused(const unsigned short* __restrict__ Qf, const unsigned short* __restrict__ Kf,
                const unsigned short* __restrict__ Vtg,
                float* __restrict__ wout, unsigned short* __restrict__ of16)
{
  __shared__ unsigned short Ks[4][32][64];   // 16 KB
  __shared__ unsigned short Vs[4][64][32];   // 16 KB
  __shared__ unsigned short PA[4][16][40];   // 5 KB
  const int tid = threadIdx.x, wid = tid >> 6, lane = tid & 63;
  const int g = lane >> 4, r16 = lane & 15;
  const int id = blockIdx.y*32 + blockIdx.x;
  const int xcd = id & 7, slot = id >> 3;
  const int bh = (slot >> 5)*8 + xcd;
  const int bx = slot & 31;
  const int bt = bh >> 4, hh = bh & (NHEAD-1);
  const int s0 = bx*64 + wid*16;
  const size_t kbase = (size_t)bh*SEQ*64;

  const size_t qoff = ((size_t)bh*SEQ + s0 + r16)*64 + (size_t)g*8;
  const f16x8 qh0 = *(const f16x8*)(Qf + qoff);      // Q pre-scaled by 0.125*log2(e)
  const f16x8 qh1 = *(const f16x8*)(Qf + qoff + 32);

  // ---- pass 1: l = sum 2^s'  (no max subtraction; scores bounded) ----
  float lp = 0.f;
  stage_k(&Ks[0][0][0], Kf, kbase, 0, tid);
  stage_k(&Ks[1][0][0], Kf, kbase, 32, tid);
  asm volatile("s_waitcnt vmcnt(1)" ::: "memory");
  __builtin_amdgcn_s_barrier();
  for (int kt = 0; kt < NT; ++kt) {
    const int cur = kt & 3;
    const bool pf = kt < NT-2;
    if (pf) stage_k(&Ks[(kt+2)&3][0][0], Kf, kbase, (kt+2)*32, tid);
#pragma unroll
    for (int sub = 0; sub < 2; ++sub) {
      const int krow = sub*16 + r16;
      const char* pk = (const char*)&Ks[cur][krow][0];
      const int sx = krow & 7;
      const f16x8 kh0 = *(const f16x8*)(pk + (((g    ) ^ sx) << 4));
      const f16x8 kh1 = *(const f16x8*)(pk + (((4 | g) ^ sx) << 4));
      f32x4 acc = {};
      __builtin_amdgcn_s_setprio(1);
      acc = mfma16(kh0, qh0, acc);
      acc = mfma16(kh1, qh1, acc);
      __builtin_amdgcn_s_setprio(0);
#pragma unroll
      for (int j = 0; j < 4; ++j) lp += __builtin_exp2f(acc[j]);
    }
    if (pf) { asm volatile("s_waitcnt vmcnt(1)" ::: "memory"); }
    else    { asm volatile("s_waitcnt vmcnt(0)" ::: "memory"); }
    __builtin_amdgcn_s_barrier();
  }
  lp += __shfl_xor(lp, 16);
  lp += __shfl_xor(lp, 32);
  const float li = 1.0f / lp;

  // ---- pass 2: weights + PV ----
  f32x4 acco[4] = {};
  char* paw = (char*)&PA[wid][0][0];

  stage_k(&Ks[0][0][0], Kf, kbase, 0, tid);
  stage_v(&Vs[0][0][0], Vtg, bh, 0, tid);
  stage_k(&Ks[1][0][0], Kf, kbase, 32, tid);
  stage_v(&Vs[1][0][0], Vtg, bh, 32, tid);
  asm volatile("s_waitcnt vmcnt(2)" ::: "memory");
  __builtin_amdgcn_s_barrier();
  for (int kt = 0; kt < NT; ++kt) {
    const int cur = kt & 3;
    const bool pf = kt < NT-2;
    if (pf) {
      stage_k(&Ks[(kt+2)&3][0][0], Kf, kbase, (kt+2)*32, tid);
      stage_v(&Vs[(kt+2)&3][0][0], Vtg, bh, (kt+2)*32, tid);
    }
#pragma unroll
    for (int sub = 0; sub < 2; ++sub) {
      const int krow = sub*16 + r16;
      const char* pk = (const char*)&Ks[cur][krow][0];
      const int sx = krow & 7;
      const f16x8 kh0 = *(const f16x8*)(pk + (((g    ) ^ sx) << 4));
      const f16x8 kh1 = *(const f16x8*)(pk + (((4 | g) ^ sx) << 4));
      f32x4 acc = {};
      __builtin_amdgcn_s_setprio(1);
      acc = mfma16(kh0, qh0, acc);
      acc = mfma16(kh1, qh1, acc);
      __builtin_amdgcn_s_setprio(0);
      f32x4 w4;
      f16x4 p4;
#pragma unroll
      for (int j = 0; j < 4; ++j) {
        w4[j] = __builtin_exp2f(acc[j]) * li;
        p4[j] = (_Float16)w4[j];
      }
      float* wp = wout + ((size_t)bh*SEQ + s0 + r16)*SEQ + kt*32 + sub*16 + 4*g;
      __builtin_nontemporal_store(w4, (f32x4*)wp);
      *(f16x4*)(paw + r16*80 + ((((2*sub + (g >> 1)) ^ (r16 & 3)) << 4) | ((g & 1) << 3))) = p4;
    }
    asm volatile("s_waitcnt lgkmcnt(0)" ::: "memory");
    const f16x8 pa = *(const f16x8*)(paw + r16*80 + ((g ^ (r16 & 3)) << 4));
    __builtin_amdgcn_s_setprio(1);
#pragma unroll
    for (int nt = 0; nt < 4; ++nt) {
      const int vrow = nt*16 + r16;
      const f16x8 vv = *(const f16x8*)((const char*)&Vs[cur][vrow][0] +
                                       ((g ^ ((vrow >> 1) & 3)) << 4));
      acco[nt] = mfma16(pa, vv, acco[nt]);
    }
    __builtin_amdgcn_s_setprio(0);
    if (pf) { asm volatile("s_waitcnt vmcnt(4)" ::: "memory"); }
    else    { asm volatile("s_waitcnt vmcnt(2)" ::: "memory"); }
    __builtin_amdgcn_s_barrier();
  }

#pragma unroll
  for (int nt = 0; nt < 4; ++nt)
#pragma unroll
    for (int j = 0; j < 4; ++j)
      of16[((size_t)bt*SEQ + s0 + 4*g + j)*DMODEL + hh*64 + nt*16 + r16] =
          __builtin_bit_cast(unsigned short, (_Float16)acco[nt][j]);
}

extern "C" void kernel_launch(void* const* d_in, const int* in_sizes, int n_in,
                              void* d_out, int out_size, void* d_ws, size_t ws_size,
                              hipStream_t stream)
{
  const float* query = (const float*)d_in[0];
  const float* key_  = (const float*)d_in[1];
  const float* value = (const float*)d_in[2];
  const float* Wq = (const float*)d_in[3];
  const float* bq = (const float*)d_in[4];
  const float* Wk = (const float*)d_in[5];
  const float* bk = (const float*)d_in[6];
  const float* Wv = (const float*)d_in[7];
  const float* bv = (const float*)d_in[8];
  const float* Wo = (const float*)d_in[9];
  const float* bo = (const float*)d_in[10];

  const size_t NE = (size_t)NBH * SEQ * 64;        // 8,388,608
  unsigned short* X16 = (unsigned short*)d_ws;     // activation f16 (reused)
  unsigned short* Qf  = X16 + NE;
  unsigned short* Kf  = Qf + NE;
  unsigned short* Vt  = Kf + NE;                   // V^T [B,H,64,S]
  unsigned short* Of  = Vt + NE;                   // attn out f16 [M][D]
  unsigned short* WH  = Of + NE;
  unsigned short* WL  = WH + (size_t)DMODEL*DMODEL;

  float* out0  = (float*)d_out;
  float* wattn = out0 + (size_t)MROWS * DMODEL;

  const int nX4 = MROWS*DMODEL/4, nW4 = DMODEL*DMODEL/4;
  const float QSCALE = 0.125f * 1.4426950408889634f;   // fold 1/sqrt(64) * log2(e)
  dim3 gg(64, 8);

  round_f16<<<1024, 256, 0, stream>>>(query, X16, nX4);
  split_f32<<<512,  256, 0, stream>>>(Wq, WH, WL, nW4);
  proj_gemm<0><<<gg, dim3(256), 0, stream>>>(X16, WH, WL, bq, QSCALE, Qf, nullptr);

  round_f16<<<1024, 256, 0, stream>>>(key_, X16, nX4);
  split_f32<<<512,  256, 0, stream>>>(Wk, WH, WL, nW4);
  proj_gemm<0><<<gg, dim3(256), 0, stream>>>(X16, WH, WL, bk, 1.0f, Kf, nullptr);

  round_f16<<<1024, 256, 0, stream>>>(value, X16, nX4);
  split_f32<<<512,  256, 0, stream>>>(Wv, WH, WL, nW4);
  proj_gemm<1><<<gg, dim3(256), 0, stream>>>(X16, WH, WL, bv, 1.0f, Vt, nullptr);

  attn_fused<<<dim3(32, NBH), dim3(256), 0, stream>>>(Qf, Kf, Vt, wattn, Of);

  split_f32<<<512,  256, 0, stream>>>(Wo, WH, WL, nW4);
  proj_gemm<2><<<gg, dim3(256), 0, stream>>>(Of, WH, WL, bo, 1.0f, nullptr, out0);
}